// Round 22
// baseline (120.130 us; speedup 1.0000x reference)
//
#include <hip/hip_runtime.h>

#define NB 8
#define NT 1024
#define NE 128
#define NH 8
#define NS 16

// Workspace layout (floats). Q/Kc/Vc/Y are each 1048576 floats (4 MB).
// Q, Kc, Vc all hold mask-COMPACTED rows (first vcount[b] valid per bh).
// vidx maps compacted position -> original t (per batch).
#define WS_Q 0
#define WS_KC 1048576
#define WS_VC 2097152
#define WS_Y 3145728
#define WS_VIDX 4194304
#define WS_VCNT (4194304 + 8192)

#define WT_PITCH 132  // multiple of 4 -> every row 16B-aligned for float4 LDS reads

typedef float v2f __attribute__((ext_vector_type(2)));

static __device__ __forceinline__ v2f vlo(const float4 v) { return v2f{v.x, v.y}; }
static __device__ __forceinline__ v2f vhi(const float4 v) { return v2f{v.z, v.w}; }
static __device__ __forceinline__ v2f pfma(v2f a, v2f b, v2f c) {
  return __builtin_elementwise_fma(a, b, c);  // v_pk_fma_f32 on gfx950
}

// fast 2^x: v_exp_f32 directly (avoids glibc __exp2f macro collision)
static __device__ __forceinline__ float fexp2(float x) {
  return __builtin_amdgcn_exp2f(x);
}

// async global->LDS, 16B per lane: dest = wave-uniform LDS base + lane*16.
// (guide §5: compiler never auto-emits this; width=16 is the proven variant)
static __device__ __forceinline__ void gload_lds16(const float* g, float* l) {
  __builtin_amdgcn_global_load_lds(
      (const __attribute__((address_space(1))) void*)g,
      (__attribute__((address_space(3))) void*)l, 16, 0, 0);
}

// packed fma4: 2 v_pk_fma_f32 instead of 4 v_fma_f32
static __device__ __forceinline__ void fma4(float4& acc, float s, const float4 v) {
  v2f lo = pfma(v2f{s, s}, vlo(v), vlo(acc));
  v2f hi = pfma(v2f{s, s}, vhi(v), vhi(acc));
  acc.x = lo.x; acc.y = lo.y; acc.z = hi.x; acc.w = hi.y;
}

// Packed-FP32 dot of two 16-float vectors.
static __device__ __forceinline__ float dot16p(const float4 q0, const float4 q1,
                                               const float4 q2, const float4 q3,
                                               const float4 k0, const float4 k1,
                                               const float4 k2, const float4 k3) {
  v2f a = vlo(q0) * vlo(k0);
  v2f b = vhi(q0) * vhi(k0);
  a = pfma(vlo(q1), vlo(k1), a);
  b = pfma(vhi(q1), vhi(k1), b);
  a = pfma(vlo(q2), vlo(k2), a);
  b = pfma(vhi(q2), vhi(k2), b);
  a = pfma(vlo(q3), vlo(k3), a);
  b = pfma(vhi(q3), vhi(k3), b);
  v2f c = a + b;
  return c.x + c.y;
}

// ---------------- Kernel A: QKV projection, ALL outputs compacted --------
// grid = 1024, 256 thr. block -> (h = blk&7, rowgroup = blk>>3 of 64 rows).
// Mask prefix (depends only on masks) -> writes Q, K, V compacted at pos;
// vidx[pos] = t. Q scale folds log2(e) for the exp2 softmax.
__global__ __launch_bounds__(256) void qkv_kernel(
    const float* __restrict__ x, const int* __restrict__ masks,
    const float* __restrict__ Wq, const float* __restrict__ Wk,
    const float* __restrict__ Wv, float* __restrict__ Q,
    float* __restrict__ Kc, float* __restrict__ Vc, int* __restrict__ vidx,
    int* __restrict__ vcount) {
  __shared__ __align__(16) float xs[64 * 20];  // 5120 B, pitch 20
  __shared__ int posl[64];
  const int tid = threadIdx.x;
  const int h = blockIdx.x & 7;
  const int rg = blockIdx.x >> 3;  // 0..127
  const int b = rg >> 4;
  const int bt = (rg & 15) << 6;  // batch-local row base
  {
    const int sr = tid >> 2, sq = tid & 3;
    float4 xv =
        *(const float4*)(x + (size_t)(b * NT + bt + sr) * 128 + h * 16 + sq * 4);
    *(float4*)(xs + sr * 20 + sq * 4) = xv;
  }
  if (tid < 64) {
    int cnt = 0;
    for (int c = 0; c < bt; c += 64)
      cnt += __popcll(__ballot(masks[b * NT + c + tid] != 0));
    int v = masks[b * NT + bt + tid] != 0;
    unsigned long long bal = __ballot(v);
    int pos = v ? (cnt + __popcll(bal & ((1ull << tid) - 1ull))) : -1;
    posl[tid] = pos;
    if (pos >= 0) vidx[b * NT + pos] = bt + tid;
    if (bt == NT - 64 && tid == 0) vcount[b] = cnt + __popcll(bal);
  }
  const int d = tid & 15;
  const int r = (tid >> 4) << 2;
  const float4* wq4 = (const float4*)(Wq + d * 16);
  const float4 wq0 = wq4[0], wq1 = wq4[1], wq2 = wq4[2], wq3 = wq4[3];
  const float4* wk4 = (const float4*)(Wk + d * 16);
  const float4 wk0 = wk4[0], wk1 = wk4[1], wk2 = wk4[2], wk3 = wk4[3];
  const float4* wv4 = (const float4*)(Wv + d * 16);
  const float4 wv0 = wv4[0], wv1 = wv4[1], wv2 = wv4[2], wv3 = wv4[3];
  // log2(e) / sqrt(128): attn computes p = exp2(q.k) = exp(q.k/sqrt(E))
  const float invs = 0.12751744448143132f;
  __syncthreads();
#pragma unroll
  for (int i = 0; i < 4; i++) {
    const int row = r + i;
    const int pp = posl[row];
    if (pp < 0) continue;  // masked row: no compacted outputs at all
    const float4* xp = (const float4*)(xs + row * 20);
    const float4 x0 = xp[0], x1 = xp[1], x2 = xp[2], x3 = xp[3];
    float aq = dot16p(x0, x1, x2, x3, wq0, wq1, wq2, wq3);
    float ak = dot16p(x0, x1, x2, x3, wk0, wk1, wk2, wk3);
    float av = dot16p(x0, x1, x2, x3, wv0, wv1, wv2, wv3);
    size_t oc = ((size_t)(b * NH + h) * NT + pp) * NS + d;
    Q[oc] = aq * invs;
    Kc[oc] = ak;
    Vc[oc] = av;
  }
}

// ---------------- Kernel B: query-compacted attention, template NQ -------
// r21 landed compaction clean (total 119.9, attn ~39 = stage 4 + DS ~22 +
// VALU ~11 + epi 2). DS is now the dominant term, and 1/3 of the block's
// DS ops are staging ds_writes (2048 of 6144 b128). Round-22: stage via
// __builtin_amdgcn_global_load_lds width=16 -- our staging layout is
// exactly the required shape (LDS dest linear in tid, per-lane global
// contiguous). 8 async direct-to-LDS ops replace 8 global loads + 8
// ds_writes per thread per chunk: DS 6144 -> 4096 per block, VGPR staging
// traffic gone. Bounds checks dropped: out-of-range rows (< NT, always
// in-bounds in the 4 MB buffer) load garbage whose sc is OVERWRITTEN with
// -1e30 before exp2 (assignment, NaN-safe).
// Carried from r21: compile-time NQ template dispatch (block-uniform);
// dynamic tiles M = nq*64; fixed-m exp2 softmax; plain-sum merge; scatter
// via vidx; fully-unrolled epilogue.
template <int NQ>
static __device__ __forceinline__ void attn_body(
    const float* __restrict__ Q, const float* __restrict__ Kc,
    const float* __restrict__ Vc, const int* __restrict__ vidx,
    float* __restrict__ Y, float* smem, const int tid, const int lane,
    const int s, const int b, const int bh, const int h, const int nv,
    const int tbase) {
  float* Ks = smem;          // [512][16]
  float* Vs = smem + 8192;   // [512][16]
  float4 q[NQ][4];
#pragma unroll
  for (int qq = 0; qq < NQ; qq++) {
    int cq = tbase + (qq << 6) + lane;
    int cqc = (cq < nv) ? cq : (nv - 1);
    const float4* qp = (const float4*)(Q + ((size_t)bh * NT + cqc) * NS);
    q[qq][0] = qp[0]; q[qq][1] = qp[1]; q[qq][2] = qp[2]; q[qq][3] = qp[3];
  }
  v2f o[NQ][8];
  float l[NQ];
#pragma unroll
  for (int qq = 0; qq < NQ; qq++) {
    l[qq] = 0.f;
#pragma unroll
    for (int k = 0; k < 8; k++) o[qq][k] = v2f{0.f, 0.f};
  }

#pragma unroll 1
  for (int k0 = 0; k0 < nv; k0 += 512) {
    const int chunk = (nv - k0 < 512) ? (nv - k0) : 512;
    __syncthreads();  // previous chunk's compute done before overwrite
    // async stage: thread tid covers bytes [p*8192 + tid*16) of each array;
    // wave-uniform LDS base = p*2048 + s*256 floats, per-lane global addr.
    {
      const float* gk = Kc + ((size_t)bh * NT + k0) * NS;
      const float* gv = Vc + ((size_t)bh * NT + k0) * NS;
      const int ge = tid << 2;        // this lane's float offset in segment 0
      const int lb = (s << 8);        // wave LDS float base in segment 0
#pragma unroll
      for (int p = 0; p < 4; p++) {
        gload_lds16(gk + (p << 11) + ge, Ks + (p << 11) + lb);
        gload_lds16(gv + (p << 11) + ge, Vs + (p << 11) + lb);
      }
    }
    __syncthreads();  // drains vmcnt (compiler emits full waitcnt)
    // barrier-free compute; unroll 2 overlaps next iter's ds_reads with
    // this iter's PV fmas (r14-proven)
#pragma unroll 2
    for (int g = 0; g < 16; g++) {
      const int rb = s + (g << 5);
      if (rb >= chunk) break;  // wave-uniform
      float sc[NQ][4];
#pragma unroll
      for (int i = 0; i < 4; i++) {
        const float4* kr = (const float4*)(Ks + (rb + (i << 3)) * 16);
        const float4 k0v = kr[0], k1v = kr[1], k2v = kr[2], k3v = kr[3];
#pragma unroll
        for (int qq = 0; qq < NQ; qq++)
          sc[qq][i] =
              dot16p(q[qq][0], q[qq][1], q[qq][2], q[qq][3], k0v, k1v, k2v, k3v);
      }
#pragma unroll
      for (int i = 0; i < 4; i++)
        if (rb + (i << 3) >= chunk) {
#pragma unroll
          for (int qq = 0; qq < NQ; qq++) sc[qq][i] = -1e30f;
        }
      float p[NQ][4];
#pragma unroll
      for (int qq = 0; qq < NQ; qq++) {
        p[qq][0] = fexp2(sc[qq][0]);
        p[qq][1] = fexp2(sc[qq][1]);
        p[qq][2] = fexp2(sc[qq][2]);
        p[qq][3] = fexp2(sc[qq][3]);
        l[qq] += (p[qq][0] + p[qq][1]) + (p[qq][2] + p[qq][3]);
      }
#pragma unroll
      for (int i = 0; i < 4; i++) {
        const float4* vr = (const float4*)(Vs + (rb + (i << 3)) * 16);
        const float4 v0 = vr[0], v1 = vr[1], v2 = vr[2], v3 = vr[3];
#pragma unroll
        for (int qq = 0; qq < NQ; qq++) {
          const v2f pq = {p[qq][i], p[qq][i]};
          o[qq][0] = pfma(pq, vlo(v0), o[qq][0]);
          o[qq][1] = pfma(pq, vhi(v0), o[qq][1]);
          o[qq][2] = pfma(pq, vlo(v1), o[qq][2]);
          o[qq][3] = pfma(pq, vhi(v1), o[qq][3]);
          o[qq][4] = pfma(pq, vlo(v2), o[qq][4]);
          o[qq][5] = pfma(pq, vhi(v2), o[qq][5]);
          o[qq][6] = pfma(pq, vlo(v3), o[qq][6]);
          o[qq][7] = pfma(pq, vhi(v3), o[qq][7]);
        }
      }
    }
  }

  // ---- epilogue: NQ fully-unrolled phases; fixed-m plain-sum merge;
  // scatter via vidx. om [8][64][20] = 40960 B aliases Ks.
  float* om = smem;
  const int q8 = tid >> 3;  // 0..63
  const int sub = tid & 7;  // 0..7
#pragma unroll
  for (int ph = 0; ph < NQ; ph++) {
    __syncthreads();  // main-loop / previous-phase reads done
    {
      float* pa = om + (s * 64 + lane) * 20;
#pragma unroll
      for (int k = 0; k < 8; k++) *(v2f*)(pa + k * 2) = o[ph][k];
      pa[16] = l[ph];
    }
    __syncthreads();
    {
      const int cq = tbase + (ph << 6) + q8;
      if (cq < nv) {
        float L = 0.f;
        v2f y = {0.f, 0.f};
#pragma unroll
        for (int ss = 0; ss < 8; ss++) {
          const float* pp = om + (ss * 64 + q8) * 20;
          L += pp[16];
          y += *(const v2f*)(pp + sub * 2);
        }
        const int tq = vidx[b * NT + cq];
        const float inv = (L > 0.f) ? (1.0f / L) : 0.f;
        y *= v2f{inv, inv};
        *(v2f*)(Y + ((size_t)b * NT + tq) * NE + h * NS + sub * 2) = y;
      }
    }
  }
}

__global__ __launch_bounds__(512, 2) void attn_kernel(
    const float* __restrict__ Q, const float* __restrict__ Kc,
    const float* __restrict__ Vc, const int* __restrict__ vidx,
    const int* __restrict__ vcount, float* __restrict__ Y) {
  __shared__ __align__(16) float smem[16384];  // 65536 B
  const int tid = threadIdx.x;
  const int lane = tid & 63;
  const int s = tid >> 6;  // key-split 0..7 (= wave id)
  const int bh = blockIdx.x & 63;
  const int qg = blockIdx.x >> 6;  // tile 0..3
  const int b = bh >> 3, h = bh & 7;
  const int nv = vcount[b];
  const int nq = (nv + 255) >> 8;  // q-slots/thread = tiles sized nq*64
  const int tbase = qg * (nq << 6);
  // block-uniform dispatch to a compile-time-NQ body (r14 codegen shape)
  if (nq == 2) {
    attn_body<2>(Q, Kc, Vc, vidx, Y, smem, tid, lane, s, b, bh, h, nv, tbase);
  } else if (nq == 3) {
    attn_body<3>(Q, Kc, Vc, vidx, Y, smem, tid, lane, s, b, bh, h, nv, tbase);
  } else if (nq == 4) {
    attn_body<4>(Q, Kc, Vc, vidx, Y, smem, tid, lane, s, b, bh, h, nv, tbase);
  } else if (nq == 1) {
    attn_body<1>(Q, Kc, Vc, vidx, Y, smem, tid, lane, s, b, bh, h, nv, tbase);
  }
  // nq == 0 (nv == 0): nothing to do; proj zeroes all masked rows.
}

// ---------------- Kernel C: out = (Y masked) @ Wu^T + bu -----------------
// grid = B*T/16 = 512 blocks, 256 threads. 16 rows/block. Masked rows of Y
// were never written by the compacted attn (stale garbage) -> zero them at
// Yt staging via mask select (r7-proven).
__global__ __launch_bounds__(256) void proj_kernel(
    const float* __restrict__ Y, const int* __restrict__ masks,
    const float* __restrict__ Wu, const float* __restrict__ bu,
    float* __restrict__ out) {
  __shared__ __align__(16) float Wt[64 * WT_PITCH];  // 33792 B
  __shared__ __align__(16) float Yt[16 * 128];       // 8192 B
  const int tid = threadIdx.x;
  const int r0 = blockIdx.x * 16;
  const float4* yg = (const float4*)(Y + (size_t)r0 * 128);
  float4* yt4 = (float4*)Yt;
  {
    const float4 z = {0, 0, 0, 0};
    const int m0 = masks[r0 + (tid >> 5)];
    const int m1 = masks[r0 + 8 + (tid >> 5)];
    float4 v0 = yg[tid];
    float4 v1 = yg[tid + 256];
    yt4[tid] = m0 ? v0 : z;
    yt4[tid + 256] = m1 ? v1 : z;
  }
  const int c0 = (tid & 31) << 2;
  const int rg = (tid >> 5) & 3;
  const int eh = tid >> 7;  // 0 or 1
  float4 acc0 = {0, 0, 0, 0}, acc1 = {0, 0, 0, 0}, acc2 = {0, 0, 0, 0},
         acc3 = {0, 0, 0, 0};
  for (int e0 = 0; e0 < 128; e0 += 64) {
    __syncthreads();  // guards Yt staging (iter 0) and Wt reuse (iter 1)
#pragma unroll
    for (int p = 0; p < 8; p++) {
      int idx = tid + p * 256;
      int c = idx >> 4;
      int es = (idx & 15) << 2;
      float4 w = *(const float4*)(Wu + c * 128 + e0 + es);
      Wt[(es + 0) * WT_PITCH + c] = w.x;
      Wt[(es + 1) * WT_PITCH + c] = w.y;
      Wt[(es + 2) * WT_PITCH + c] = w.z;
      Wt[(es + 3) * WT_PITCH + c] = w.w;
    }
    __syncthreads();
    const int eb = eh << 5;  // this thread's e-half within the 64-chunk
    const float* y0 = Yt + (rg * 4 + 0) * 128 + e0 + eb;
    const float* y1 = Yt + (rg * 4 + 1) * 128 + e0 + eb;
    const float* y2 = Yt + (rg * 4 + 2) * 128 + e0 + eb;
    const float* y3 = Yt + (rg * 4 + 3) * 128 + e0 + eb;
#pragma unroll 4
    for (int e = 0; e < 32; e += 4) {
      const float* wb = Wt + (eb + e) * WT_PITCH + c0;
      float4 w0 = *(const float4*)(wb + 0 * WT_PITCH);
      float4 w1 = *(const float4*)(wb + 1 * WT_PITCH);
      float4 w2 = *(const float4*)(wb + 2 * WT_PITCH);
      float4 w3 = *(const float4*)(wb + 3 * WT_PITCH);
      float4 ya = *(const float4*)(y0 + e);
      float4 yb = *(const float4*)(y1 + e);
      float4 yc = *(const float4*)(y2 + e);
      float4 yd = *(const float4*)(y3 + e);
      fma4(acc0, ya.x, w0); fma4(acc0, ya.y, w1); fma4(acc0, ya.z, w2); fma4(acc0, ya.w, w3);
      fma4(acc1, yb.x, w0); fma4(acc1, yb.y, w1); fma4(acc1, yb.z, w2); fma4(acc1, yb.w, w3);
      fma4(acc2, yc.x, w0); fma4(acc2, yc.y, w1); fma4(acc2, yc.z, w2); fma4(acc2, yc.w, w3);
      fma4(acc3, yd.x, w0); fma4(acc3, yd.y, w1); fma4(acc3, yd.z, w2); fma4(acc3, yd.w, w3);
    }
  }
  // combine e-halves through LDS (Wt dead; pitch 20 to spread banks)
  __syncthreads();
  if (eh == 1) {
    float* p = Wt + (tid & 127) * 20;
    *(float4*)(p + 0) = acc0; *(float4*)(p + 4) = acc1;
    *(float4*)(p + 8) = acc2; *(float4*)(p + 12) = acc3;
  }
  __syncthreads();
  if (eh == 0) {
    const float* p = Wt + tid * 20;
    float4 b4 = *(const float4*)(bu + c0);
    float4 q0 = *(const float4*)(p + 0);
    float4 q1 = *(const float4*)(p + 4);
    float4 q2 = *(const float4*)(p + 8);
    float4 q3 = *(const float4*)(p + 12);
    acc0.x += q0.x + b4.x; acc0.y += q0.y + b4.y; acc0.z += q0.z + b4.z; acc0.w += q0.w + b4.w;
    acc1.x += q1.x + b4.x; acc1.y += q1.y + b4.y; acc1.z += q1.z + b4.z; acc1.w += q1.w + b4.w;
    acc2.x += q2.x + b4.x; acc2.y += q2.y + b4.y; acc2.z += q2.z + b4.z; acc2.w += q2.w + b4.w;
    acc3.x += q3.x + b4.x; acc3.y += q3.y + b4.y; acc3.z += q3.z + b4.z; acc3.w += q3.w + b4.w;
    *(float4*)(out + (size_t)(r0 + rg * 4 + 0) * 128 + c0) = acc0;
    *(float4*)(out + (size_t)(r0 + rg * 4 + 1) * 128 + c0) = acc1;
    *(float4*)(out + (size_t)(r0 + rg * 4 + 2) * 128 + c0) = acc2;
    *(float4*)(out + (size_t)(r0 + rg * 4 + 3) * 128 + c0) = acc3;
  }
}

extern "C" void kernel_launch(void* const* d_in, const int* in_sizes, int n_in,
                              void* d_out, int out_size, void* d_ws,
                              size_t ws_size, hipStream_t stream) {
  const float* x = (const float*)d_in[0];
  const int* masks = (const int*)d_in[1];
  const float* Wq = (const float*)d_in[2];
  const float* Wk = (const float*)d_in[3];
  const float* Wv = (const float*)d_in[4];
  const float* Wu = (const float*)d_in[5];
  const float* bu = (const float*)d_in[6];
  float* out = (float*)d_out;

  float* ws = (float*)d_ws;
  float* Q = ws + WS_Q;
  float* Kc = ws + WS_KC;
  float* Vc = ws + WS_VC;
  float* Y = ws + WS_Y;
  int* vidx = (int*)(ws + WS_VIDX);
  int* vcount = (int*)(ws + WS_VCNT);

  qkv_kernel<<<1024, 256, 0, stream>>>(x, masks, Wq, Wk, Wv, Q, Kc, Vc, vidx,
                                       vcount);
  // grid = 4 dynamic tiles x 64 bh = 256 blocks (1/CU), 512 thr
  attn_kernel<<<4 * NB * NH, 512, 0, stream>>>(Q, Kc, Vc, vidx, vcount, Y);
  proj_kernel<<<NB * NT / 16, 256, 0, stream>>>(Y, masks, Wu, bu, out);
}

// Round 23
// 119.470 us; speedup vs baseline: 1.0055x; 1.0055x over previous
//
#include <hip/hip_runtime.h>

#define NB 8
#define NT 1024
#define NE 128
#define NH 8
#define NS 16

// Workspace (floats). Q/Kc/Vc compacted (4 MB each); Y0/Y1 raw per-key-half
// partial outputs (4 MB each); L0/L1 per-half softmax denominators; vidx maps
// compacted pos -> t; vcount. Fixed-m softmax -> halves merge by plain sum.
#define WS_Q 0
#define WS_KC 1048576
#define WS_VC 2097152
#define WS_Y0 3145728
#define WS_Y1 4194304
#define WS_L0 5242880
#define WS_L1 (5242880 + 65536)
#define WS_VIDX (5242880 + 131072)
#define WS_VCNT (5242880 + 131072 + 8192)

#define WT_PITCH 132  // multiple of 4 -> every row 16B-aligned for float4 LDS reads

typedef float v2f __attribute__((ext_vector_type(2)));

static __device__ __forceinline__ v2f vlo(const float4 v) { return v2f{v.x, v.y}; }
static __device__ __forceinline__ v2f vhi(const float4 v) { return v2f{v.z, v.w}; }
static __device__ __forceinline__ v2f pfma(v2f a, v2f b, v2f c) {
  return __builtin_elementwise_fma(a, b, c);  // v_pk_fma_f32 on gfx950
}

// fast 2^x: v_exp_f32 directly (avoids glibc __exp2f macro collision)
static __device__ __forceinline__ float fexp2(float x) {
  return __builtin_amdgcn_exp2f(x);
}

// async global->LDS, 16B per lane (r22-proven)
static __device__ __forceinline__ void gload_lds16(const float* g, float* l) {
  __builtin_amdgcn_global_load_lds(
      (const __attribute__((address_space(1))) void*)g,
      (__attribute__((address_space(3))) void*)l, 16, 0, 0);
}

// packed fma4: 2 v_pk_fma_f32 instead of 4 v_fma_f32
static __device__ __forceinline__ void fma4(float4& acc, float s, const float4 v) {
  v2f lo = pfma(v2f{s, s}, vlo(v), vlo(acc));
  v2f hi = pfma(v2f{s, s}, vhi(v), vhi(acc));
  acc.x = lo.x; acc.y = lo.y; acc.z = hi.x; acc.w = hi.y;
}

// Packed-FP32 dot of two 16-float vectors.
static __device__ __forceinline__ float dot16p(const float4 q0, const float4 q1,
                                               const float4 q2, const float4 q3,
                                               const float4 k0, const float4 k1,
                                               const float4 k2, const float4 k3) {
  v2f a = vlo(q0) * vlo(k0);
  v2f b = vhi(q0) * vhi(k0);
  a = pfma(vlo(q1), vlo(k1), a);
  b = pfma(vhi(q1), vhi(k1), b);
  a = pfma(vlo(q2), vlo(k2), a);
  b = pfma(vhi(q2), vhi(k2), b);
  a = pfma(vlo(q3), vlo(k3), a);
  b = pfma(vhi(q3), vhi(k3), b);
  v2f c = a + b;
  return c.x + c.y;
}

// ---------------- Kernel A: QKV projection, ALL outputs compacted --------
// (r21/r22-proven) grid = 1024, 256 thr. Mask prefix -> Q/Kc/Vc compacted;
// vidx[pos] = t. Q scale folds log2(e) for the exp2 softmax.
__global__ __launch_bounds__(256) void qkv_kernel(
    const float* __restrict__ x, const int* __restrict__ masks,
    const float* __restrict__ Wq, const float* __restrict__ Wk,
    const float* __restrict__ Wv, float* __restrict__ Q,
    float* __restrict__ Kc, float* __restrict__ Vc, int* __restrict__ vidx,
    int* __restrict__ vcount) {
  __shared__ __align__(16) float xs[64 * 20];  // 5120 B, pitch 20
  __shared__ int posl[64];
  const int tid = threadIdx.x;
  const int h = blockIdx.x & 7;
  const int rg = blockIdx.x >> 3;  // 0..127
  const int b = rg >> 4;
  const int bt = (rg & 15) << 6;  // batch-local row base
  {
    const int sr = tid >> 2, sq = tid & 3;
    float4 xv =
        *(const float4*)(x + (size_t)(b * NT + bt + sr) * 128 + h * 16 + sq * 4);
    *(float4*)(xs + sr * 20 + sq * 4) = xv;
  }
  if (tid < 64) {
    int cnt = 0;
    for (int c = 0; c < bt; c += 64)
      cnt += __popcll(__ballot(masks[b * NT + c + tid] != 0));
    int v = masks[b * NT + bt + tid] != 0;
    unsigned long long bal = __ballot(v);
    int pos = v ? (cnt + __popcll(bal & ((1ull << tid) - 1ull))) : -1;
    posl[tid] = pos;
    if (pos >= 0) vidx[b * NT + pos] = bt + tid;
    if (bt == NT - 64 && tid == 0) vcount[b] = cnt + __popcll(bal);
  }
  const int d = tid & 15;
  const int r = (tid >> 4) << 2;
  const float4* wq4 = (const float4*)(Wq + d * 16);
  const float4 wq0 = wq4[0], wq1 = wq4[1], wq2 = wq4[2], wq3 = wq4[3];
  const float4* wk4 = (const float4*)(Wk + d * 16);
  const float4 wk0 = wk4[0], wk1 = wk4[1], wk2 = wk4[2], wk3 = wk4[3];
  const float4* wv4 = (const float4*)(Wv + d * 16);
  const float4 wv0 = wv4[0], wv1 = wv4[1], wv2 = wv4[2], wv3 = wv4[3];
  // log2(e) / sqrt(128): attn computes p = exp2(q.k) = exp(q.k/sqrt(E))
  const float invs = 0.12751744448143132f;
  __syncthreads();
#pragma unroll
  for (int i = 0; i < 4; i++) {
    const int row = r + i;
    const int pp = posl[row];
    if (pp < 0) continue;  // masked row: no compacted outputs at all
    const float4* xp = (const float4*)(xs + row * 20);
    const float4 x0 = xp[0], x1 = xp[1], x2 = xp[2], x3 = xp[3];
    float aq = dot16p(x0, x1, x2, x3, wq0, wq1, wq2, wq3);
    float ak = dot16p(x0, x1, x2, x3, wk0, wk1, wk2, wk3);
    float av = dot16p(x0, x1, x2, x3, wv0, wv1, wv2, wv3);
    size_t oc = ((size_t)(b * NH + h) * NT + pp) * NS + d;
    Q[oc] = aq * invs;
    Kc[oc] = ak;
    Vc[oc] = av;
  }
}

// ---------------- Kernel B: query-compacted + KEY-HALVED attention -------
// r22 post-mortem: attn ~39 = stage(2-4) + DS-read(20: nv x 8 b128
// broadcasts) + VALU(11) + epi(2); the DS term scales with KEYS PER BLOCK.
// Round-23 re-partitions the same 256 blocks as 2 query-tiles x 2 key-
// halves x 64 bh: each block reads only nv/2 keys -> per-block DS halves
// (~10us) at 1 block/CU (no shared-pipe serialization, the r17 trap).
// Queries/tile double (template NQ = ceil(nv/128) ~ 4 = r14's register
// shape); per-block VALU = 2x queries x 1/2 keys = unchanged ~10.5us.
// Key-half merge: raw partials to Y0/Y1 + L0/L1 (no atomics, r18-proven),
// plain-sum in proj (fixed-m softmax). Each half <= 512 rows -> single
// stage (no chunk loop); only ceil(chunk/128) async segments issued.
template <int NQ>
static __device__ __forceinline__ void attn_body(
    const float* __restrict__ Q, const float* __restrict__ Kc,
    const float* __restrict__ Vc, const int* __restrict__ vidx,
    float* __restrict__ Yh, float* __restrict__ Lh, float* smem,
    const int tid, const int lane, const int s, const int b, const int bh,
    const int h, const int nv, const int tbase, const int kstart,
    const int kend) {
  float* Ks = smem;          // [512][16]
  float* Vs = smem + 8192;   // [512][16]
  float4 q[NQ][4];
#pragma unroll
  for (int qq = 0; qq < NQ; qq++) {
    int cq = tbase + (qq << 6) + lane;
    int cqc = (cq < nv) ? cq : (nv - 1);
    const float4* qp = (const float4*)(Q + ((size_t)bh * NT + cqc) * NS);
    q[qq][0] = qp[0]; q[qq][1] = qp[1]; q[qq][2] = qp[2]; q[qq][3] = qp[3];
  }
  v2f o[NQ][8];
  float l[NQ];
#pragma unroll
  for (int qq = 0; qq < NQ; qq++) {
    l[qq] = 0.f;
#pragma unroll
    for (int k = 0; k < 8; k++) o[qq][k] = v2f{0.f, 0.f};
  }

  const int chunk = kend - kstart;  // 0..512, block-uniform
  if (chunk > 0) {
    // async stage: segment p covers rows [p*128, p*128+128); issue only
    // the segments that intersect [0, chunk).
    const int nseg = (chunk + 127) >> 7;
    const float* gk = Kc + ((size_t)bh * NT + kstart) * NS;
    const float* gv = Vc + ((size_t)bh * NT + kstart) * NS;
    const int ge = tid << 2;  // lane float offset within a segment
    const int lb = s << 8;    // wave LDS float base within a segment
#pragma unroll 1
    for (int p = 0; p < nseg; p++) {
      gload_lds16(gk + (p << 11) + ge, Ks + (p << 11) + lb);
      gload_lds16(gv + (p << 11) + ge, Vs + (p << 11) + lb);
    }
  }
  __syncthreads();  // drains async loads (compiler emits full waitcnt)

  // barrier-free compute; unroll 2 overlaps next iter's ds_reads with this
  // iter's PV fmas (r14-proven). Rows past chunk masked via sc = -1e30.
#pragma unroll 2
  for (int g = 0; g < 16; g++) {
    const int rb = s + (g << 5);
    if (rb >= chunk) break;  // wave-uniform
    float sc[NQ][4];
#pragma unroll
    for (int i = 0; i < 4; i++) {
      const float4* kr = (const float4*)(Ks + (rb + (i << 3)) * 16);
      const float4 k0v = kr[0], k1v = kr[1], k2v = kr[2], k3v = kr[3];
#pragma unroll
      for (int qq = 0; qq < NQ; qq++)
        sc[qq][i] =
            dot16p(q[qq][0], q[qq][1], q[qq][2], q[qq][3], k0v, k1v, k2v, k3v);
    }
#pragma unroll
    for (int i = 0; i < 4; i++)
      if (rb + (i << 3) >= chunk) {
#pragma unroll
        for (int qq = 0; qq < NQ; qq++) sc[qq][i] = -1e30f;
      }
    float p[NQ][4];
#pragma unroll
    for (int qq = 0; qq < NQ; qq++) {
      p[qq][0] = fexp2(sc[qq][0]);
      p[qq][1] = fexp2(sc[qq][1]);
      p[qq][2] = fexp2(sc[qq][2]);
      p[qq][3] = fexp2(sc[qq][3]);
      l[qq] += (p[qq][0] + p[qq][1]) + (p[qq][2] + p[qq][3]);
    }
#pragma unroll
    for (int i = 0; i < 4; i++) {
      const float4* vr = (const float4*)(Vs + (rb + (i << 3)) * 16);
      const float4 v0 = vr[0], v1 = vr[1], v2 = vr[2], v3 = vr[3];
#pragma unroll
      for (int qq = 0; qq < NQ; qq++) {
        const v2f pq = {p[qq][i], p[qq][i]};
        o[qq][0] = pfma(pq, vlo(v0), o[qq][0]);
        o[qq][1] = pfma(pq, vhi(v0), o[qq][1]);
        o[qq][2] = pfma(pq, vlo(v1), o[qq][2]);
        o[qq][3] = pfma(pq, vhi(v1), o[qq][3]);
        o[qq][4] = pfma(pq, vlo(v2), o[qq][4]);
        o[qq][5] = pfma(pq, vhi(v2), o[qq][5]);
        o[qq][6] = pfma(pq, vlo(v3), o[qq][6]);
        o[qq][7] = pfma(pq, vhi(v3), o[qq][7]);
      }
    }
  }

  // ---- epilogue: NQ fully-unrolled phases; RAW partial sums to Yh/Lh
  // (no normalization -- proj merges halves and normalizes). om [8][64][20]
  // = 40960 B aliases Ks; barrier before reuse.
  float* om = smem;
  const int q8 = tid >> 3;  // 0..63
  const int sub = tid & 7;  // 0..7
#pragma unroll
  for (int ph = 0; ph < NQ; ph++) {
    __syncthreads();  // main-loop / previous-phase reads done
    {
      float* pa = om + (s * 64 + lane) * 20;
#pragma unroll
      for (int k = 0; k < 8; k++) *(v2f*)(pa + k * 2) = o[ph][k];
      pa[16] = l[ph];
    }
    __syncthreads();
    {
      const int cq = tbase + (ph << 6) + q8;
      if (cq < nv) {
        float L = 0.f;
        v2f y = {0.f, 0.f};
#pragma unroll
        for (int ss = 0; ss < 8; ss++) {
          const float* pp = om + (ss * 64 + q8) * 20;
          L += pp[16];
          y += *(const v2f*)(pp + sub * 2);
        }
        const int tq = vidx[b * NT + cq];
        *(v2f*)(Yh + ((size_t)b * NT + tq) * NE + h * NS + sub * 2) = y;
        if (sub == 0) Lh[(size_t)bh * NT + tq] = L;
      }
    }
  }
}

__global__ __launch_bounds__(512, 2) void attn_kernel(
    const float* __restrict__ Q, const float* __restrict__ Kc,
    const float* __restrict__ Vc, const int* __restrict__ vidx,
    const int* __restrict__ vcount, float* __restrict__ Y0,
    float* __restrict__ Y1, float* __restrict__ L0, float* __restrict__ L1) {
  __shared__ __align__(16) float smem[16384];  // 65536 B
  const int tid = threadIdx.x;
  const int lane = tid & 63;
  const int s = tid >> 6;  // key-split wave 0..7
  const int bh = blockIdx.x & 63;
  const int tile = (blockIdx.x >> 6) & 1;  // query tile 0/1
  const int kh = blockIdx.x >> 7;          // key half 0/1
  const int b = bh >> 3, h = bh & 7;
  const int nv = vcount[b];
  const int nq = (nv + 127) >> 7;  // q-slots/thread; 2 tiles cover nv
  const int tbase = tile * (nq << 6);
  const int h0 = nv >> 1;
  const int kstart = kh ? h0 : 0;
  const int kend = kh ? nv : h0;
  float* Yh = kh ? Y1 : Y0;
  float* Lh = kh ? L1 : L0;
  // block-uniform dispatch to compile-time-NQ bodies (r21-proven pattern);
  // order by likelihood for nv ~ Binomial(1024, 0.5).
  if (nq == 4) {
    attn_body<4>(Q, Kc, Vc, vidx, Yh, Lh, smem, tid, lane, s, b, bh, h, nv,
                 tbase, kstart, kend);
  } else if (nq == 5) {
    attn_body<5>(Q, Kc, Vc, vidx, Yh, Lh, smem, tid, lane, s, b, bh, h, nv,
                 tbase, kstart, kend);
  } else if (nq == 3) {
    attn_body<3>(Q, Kc, Vc, vidx, Yh, Lh, smem, tid, lane, s, b, bh, h, nv,
                 tbase, kstart, kend);
  } else if (nq == 2) {
    attn_body<2>(Q, Kc, Vc, vidx, Yh, Lh, smem, tid, lane, s, b, bh, h, nv,
                 tbase, kstart, kend);
  } else if (nq == 6) {
    attn_body<6>(Q, Kc, Vc, vidx, Yh, Lh, smem, tid, lane, s, b, bh, h, nv,
                 tbase, kstart, kend);
  } else if (nq == 1) {
    attn_body<1>(Q, Kc, Vc, vidx, Yh, Lh, smem, tid, lane, s, b, bh, h, nv,
                 tbase, kstart, kend);
  } else if (nq == 7) {
    attn_body<7>(Q, Kc, Vc, vidx, Yh, Lh, smem, tid, lane, s, b, bh, h, nv,
                 tbase, kstart, kend);
  } else if (nq == 8) {
    attn_body<8>(Q, Kc, Vc, vidx, Yh, Lh, smem, tid, lane, s, b, bh, h, nv,
                 tbase, kstart, kend);
  }
  // nq == 0 (nv == 0): nothing to do; proj zeroes all masked rows.
}

// ---------------- Kernel C: out = ((Y0+Y1)/(L0+L1) masked) @ Wu^T + bu ---
// grid = B*T/16 = 512 blocks, 256 threads. Key-half merge (plain sum,
// fixed-m softmax) + normalization + query-mask select (guards stale
// garbage incl. NaN) happen at Yt staging.
__global__ __launch_bounds__(256) void proj_kernel(
    const float* __restrict__ Y0, const float* __restrict__ Y1,
    const float* __restrict__ L0, const float* __restrict__ L1,
    const int* __restrict__ masks, const float* __restrict__ Wu,
    const float* __restrict__ bu, float* __restrict__ out) {
  __shared__ __align__(16) float Wt[64 * WT_PITCH];  // 33792 B
  __shared__ __align__(16) float Yt[16 * 128];       // 8192 B
  const int tid = threadIdx.x;
  const int r0 = blockIdx.x * 16;
  const int bb = r0 >> 10;  // batch (16-row blocks never straddle batches)
  const float4* yg0 = (const float4*)(Y0 + (size_t)r0 * 128);
  const float4* yg1 = (const float4*)(Y1 + (size_t)r0 * 128);
  float4* yt4 = (float4*)Yt;
  {
    const float4 z = {0, 0, 0, 0};
#pragma unroll
    for (int p = 0; p < 2; p++) {
      const int idx = tid + p * 256;
      const int row = idx >> 5;          // 0..15
      const int head = (idx & 31) >> 2;  // 0..7
      const int t = (r0 + row) & 1023;
      const size_t li = (size_t)(bb * NH + head) * NT + t;
      const int qm = masks[r0 + row];
      const float Lv = L0[li] + L1[li];
      const float inv = (qm != 0 && Lv > 0.f) ? (1.0f / Lv) : 0.f;
      float4 a = yg0[idx];
      float4 c = yg1[idx];
      a.x = (a.x + c.x) * inv; a.y = (a.y + c.y) * inv;
      a.z = (a.z + c.z) * inv; a.w = (a.w + c.w) * inv;
      yt4[idx] = qm ? a : z;  // select, not multiply: NaN-garbage safe
    }
  }
  const int c0 = (tid & 31) << 2;
  const int rg = (tid >> 5) & 3;
  const int eh = tid >> 7;  // 0 or 1
  float4 acc0 = {0, 0, 0, 0}, acc1 = {0, 0, 0, 0}, acc2 = {0, 0, 0, 0},
         acc3 = {0, 0, 0, 0};
  for (int e0 = 0; e0 < 128; e0 += 64) {
    __syncthreads();  // guards Yt staging (iter 0) and Wt reuse (iter 1)
#pragma unroll
    for (int p = 0; p < 8; p++) {
      int idx = tid + p * 256;
      int c = idx >> 4;
      int es = (idx & 15) << 2;
      float4 w = *(const float4*)(Wu + c * 128 + e0 + es);
      Wt[(es + 0) * WT_PITCH + c] = w.x;
      Wt[(es + 1) * WT_PITCH + c] = w.y;
      Wt[(es + 2) * WT_PITCH + c] = w.z;
      Wt[(es + 3) * WT_PITCH + c] = w.w;
    }
    __syncthreads();
    const int eb = eh << 5;  // this thread's e-half within the 64-chunk
    const float* y0 = Yt + (rg * 4 + 0) * 128 + e0 + eb;
    const float* y1 = Yt + (rg * 4 + 1) * 128 + e0 + eb;
    const float* y2 = Yt + (rg * 4 + 2) * 128 + e0 + eb;
    const float* y3 = Yt + (rg * 4 + 3) * 128 + e0 + eb;
#pragma unroll 4
    for (int e = 0; e < 32; e += 4) {
      const float* wb = Wt + (eb + e) * WT_PITCH + c0;
      float4 w0 = *(const float4*)(wb + 0 * WT_PITCH);
      float4 w1 = *(const float4*)(wb + 1 * WT_PITCH);
      float4 w2 = *(const float4*)(wb + 2 * WT_PITCH);
      float4 w3 = *(const float4*)(wb + 3 * WT_PITCH);
      float4 ya = *(const float4*)(y0 + e);
      float4 yb = *(const float4*)(y1 + e);
      float4 yc = *(const float4*)(y2 + e);
      float4 yd = *(const float4*)(y3 + e);
      fma4(acc0, ya.x, w0); fma4(acc0, ya.y, w1); fma4(acc0, ya.z, w2); fma4(acc0, ya.w, w3);
      fma4(acc1, yb.x, w0); fma4(acc1, yb.y, w1); fma4(acc1, yb.z, w2); fma4(acc1, yb.w, w3);
      fma4(acc2, yc.x, w0); fma4(acc2, yc.y, w1); fma4(acc2, yc.z, w2); fma4(acc2, yc.w, w3);
      fma4(acc3, yd.x, w0); fma4(acc3, yd.y, w1); fma4(acc3, yd.z, w2); fma4(acc3, yd.w, w3);
    }
  }
  // combine e-halves through LDS (Wt dead; pitch 20 to spread banks)
  __syncthreads();
  if (eh == 1) {
    float* p = Wt + (tid & 127) * 20;
    *(float4*)(p + 0) = acc0; *(float4*)(p + 4) = acc1;
    *(float4*)(p + 8) = acc2; *(float4*)(p + 12) = acc3;
  }
  __syncthreads();
  if (eh == 0) {
    const float* p = Wt + tid * 20;
    float4 b4 = *(const float4*)(bu + c0);
    float4 q0 = *(const float4*)(p + 0);
    float4 q1 = *(const float4*)(p + 4);
    float4 q2 = *(const float4*)(p + 8);
    float4 q3 = *(const float4*)(p + 12);
    acc0.x += q0.x + b4.x; acc0.y += q0.y + b4.y; acc0.z += q0.z + b4.z; acc0.w += q0.w + b4.w;
    acc1.x += q1.x + b4.x; acc1.y += q1.y + b4.y; acc1.z += q1.z + b4.z; acc1.w += q1.w + b4.w;
    acc2.x += q2.x + b4.x; acc2.y += q2.y + b4.y; acc2.z += q2.z + b4.z; acc2.w += q2.w + b4.w;
    acc3.x += q3.x + b4.x; acc3.y += q3.y + b4.y; acc3.z += q3.z + b4.z; acc3.w += q3.w + b4.w;
    *(float4*)(out + (size_t)(r0 + rg * 4 + 0) * 128 + c0) = acc0;
    *(float4*)(out + (size_t)(r0 + rg * 4 + 1) * 128 + c0) = acc1;
    *(float4*)(out + (size_t)(r0 + rg * 4 + 2) * 128 + c0) = acc2;
    *(float4*)(out + (size_t)(r0 + rg * 4 + 3) * 128 + c0) = acc3;
  }
}

extern "C" void kernel_launch(void* const* d_in, const int* in_sizes, int n_in,
                              void* d_out, int out_size, void* d_ws,
                              size_t ws_size, hipStream_t stream) {
  const float* x = (const float*)d_in[0];
  const int* masks = (const int*)d_in[1];
  const float* Wq = (const float*)d_in[2];
  const float* Wk = (const float*)d_in[3];
  const float* Wv = (const float*)d_in[4];
  const float* Wu = (const float*)d_in[5];
  const float* bu = (const float*)d_in[6];
  float* out = (float*)d_out;

  float* ws = (float*)d_ws;
  float* Q = ws + WS_Q;
  float* Kc = ws + WS_KC;
  float* Vc = ws + WS_VC;
  float* Y0 = ws + WS_Y0;
  float* Y1 = ws + WS_Y1;
  float* L0 = ws + WS_L0;
  float* L1 = ws + WS_L1;
  int* vidx = (int*)(ws + WS_VIDX);
  int* vcount = (int*)(ws + WS_VCNT);

  qkv_kernel<<<1024, 256, 0, stream>>>(x, masks, Wq, Wk, Wv, Q, Kc, Vc, vidx,
                                       vcount);
  // grid = 2 key-halves x 2 query-tiles x 64 bh = 256 blocks (1/CU), 512 thr
  attn_kernel<<<256, 512, 0, stream>>>(Q, Kc, Vc, vidx, vcount, Y0, Y1, L0,
                                       L1);
  proj_kernel<<<NB * NT / 16, 256, 0, stream>>>(Y0, Y1, L0, L1, masks, Wu, bu,
                                                out);
}